// Round 4
// baseline (65.276 us; speedup 1.0000x reference)
//
#include <hip/hip_runtime.h>

// Problem constants (B=2, C=32, H=W=64, P=3, D=7, K=4)
constexpr int NPIX = 2 * 64 * 64;   // 8192 pixels
constexpr float EPSF = 1e-12f;

// ws layout (floats):
constexpr int WS_WGT = 0;          // 8192*288 [pix][j*32 + c]
constexpr int WS_SIM = 2359296;    // 8192*64  [pix][uv], raw 3x3 box-dot
constexpr int WS_F1T = 2883584;    // 8192*32  [pix][c]  channel-last ftm1
constexpr int WS_RBN = 3145728;    // 8192     1/max(||patch(ftm1)||,eps)
constexpr int WS_FTT = 3153920;    // 8192*32  [pix][c]  channel-last ft
constexpr int WS_N   = 3416064;    // 8192     per-pixel sum_c ftm1^2
constexpr int WS_NEED = 3424256;

// ---------------------------------------------------------------------------
// Transpose kernel: one block per (b, y) row. Builds channel-last copies of
// ft and ftm1 (coalesced both sides via LDS tile) + per-pixel N = sum_c f1^2.
// ---------------------------------------------------------------------------
__global__ __launch_bounds__(256) void trans_kernel(
    const float* __restrict__ ft, const float* __restrict__ ftm1,
    float* __restrict__ ws)
{
    __shared__ float tile[32][65];
    __shared__ float part[4][64];
    const int t = threadIdx.x;
    const int b = blockIdx.x >> 6;
    const int y = blockIdx.x & 63;
    const int x = t & 63;
    const int cg = t >> 6;               // 0..3
    const int rowoff = (y << 6) + x;
    const float* ftb = ft   + ((size_t)b << 17) + rowoff;
    const float* f1b = ftm1 + ((size_t)b << 17) + rowoff;

    // ---- ft -> ft_t ----
    #pragma unroll
    for (int i = 0; i < 8; ++i)
        tile[cg * 8 + i][x] = ftb[(size_t)(cg * 8 + i) << 12];
    __syncthreads();
    {
        float4* dst = reinterpret_cast<float4*>(ws + WS_FTT)
                    + ((size_t)((b << 12) + (y << 6)) << 3);
        #pragma unroll
        for (int s = 0; s < 2; ++s) {
            int idx = t + s * 256;       // 0..511 = px*8 + chunk
            int px = idx >> 3, ch = (idx & 7) << 2;
            float4 q;
            q.x = tile[ch + 0][px]; q.y = tile[ch + 1][px];
            q.z = tile[ch + 2][px]; q.w = tile[ch + 3][px];
            dst[idx] = q;
        }
    }
    __syncthreads();

    // ---- ftm1 -> f1t (+ N) ----
    float nsum = 0.f;
    #pragma unroll
    for (int i = 0; i < 8; ++i) {
        float v = f1b[(size_t)(cg * 8 + i) << 12];
        tile[cg * 8 + i][x] = v;
        nsum += v * v;
    }
    part[cg][x] = nsum;
    __syncthreads();
    {
        float4* dst = reinterpret_cast<float4*>(ws + WS_F1T)
                    + ((size_t)((b << 12) + (y << 6)) << 3);
        #pragma unroll
        for (int s = 0; s < 2; ++s) {
            int idx = t + s * 256;
            int px = idx >> 3, ch = (idx & 7) << 2;
            float4 q;
            q.x = tile[ch + 0][px]; q.y = tile[ch + 1][px];
            q.z = tile[ch + 2][px]; q.w = tile[ch + 3][px];
            dst[idx] = q;
        }
    }
    if (t < 64) {
        float nn = (part[0][t] + part[1][t]) + (part[2][t] + part[3][t]);
        (ws + WS_N)[(b << 12) + (y << 6) + t] = nn;
    }
}

// ---------------------------------------------------------------------------
// wgt kernel (r2 vector-load structure + unroll-4, stores [pix][j*32+c]).
// ---------------------------------------------------------------------------
__global__ __launch_bounds__(256) void wgt_kernel(
    const float* __restrict__ feat_t, const float* __restrict__ feat_tm1,
    const float* __restrict__ wproj_w, const float* __restrict__ wproj_b,
    float* __restrict__ wgt_ws)
{
    __shared__ __align__(16) float catl[64 * 16];    // [i][px]
    __shared__ __align__(16) float wtile[16 * 289];  // [px][o] padded

    const int t = threadIdx.x;
    const int base = blockIdx.x * 16;       // 16 consecutive pixels, same row
    const int b  = base >> 12;
    const int y  = (base >> 6) & 63;
    const int x0 = base & 63;

    for (int idx = t; idx < 64 * 16; idx += 256) {
        int i = idx >> 4, px = idx & 15;
        const float* src = (i < 32) ? feat_t : feat_tm1;
        catl[idx] = src[((b * 32 + (i & 31)) << 12) + (y << 6) + x0 + px];
    }
    __syncthreads();

    const int px = t & 15, og = t >> 4;     // og in 0..15, 18 outputs each
    float acc[18];
    #pragma unroll
    for (int j = 0; j < 18; ++j) acc[j] = wproj_b[og * 18 + j];

    const float4* w4 = reinterpret_cast<const float4*>(wproj_w);
    #pragma unroll 4
    for (int i = 0; i < 64; i += 4) {
        float c0 = catl[(i + 0) * 16 + px];
        float c1 = catl[(i + 1) * 16 + px];
        float c2 = catl[(i + 2) * 16 + px];
        float c3 = catl[(i + 3) * 16 + px];
        #pragma unroll
        for (int j = 0; j < 18; ++j) {
            float4 wv = w4[(og * 18 + j) * 16 + (i >> 2)];
            acc[j] += wv.x * c0 + wv.y * c1 + wv.z * c2 + wv.w * c3;
        }
    }
    #pragma unroll
    for (int j = 0; j < 18; ++j) wtile[px * 289 + og * 18 + j] = acc[j];
    __syncthreads();

    for (int idx = t; idx < 16 * 288; idx += 256) {
        int p = idx / 288, o = idx - p * 288;
        int c = o / 9, jj = o - c * 9;
        wgt_ws[(size_t)(base + p) * 288 + jj * 32 + c] = wtile[p * 289 + o];
    }
}

// ---------------------------------------------------------------------------
// sim kernel: channel-last contiguous dwordx4 loads. Blocks 0..783: sim for
// one (b, uv, 8-row band). Blocks 784..815: rBN = rsqrt(box3(N)).
// ---------------------------------------------------------------------------
__global__ __launch_bounds__(256) void sim_kernel(float* __restrict__ ws)
{
    __shared__ float sbuf[10 * 64];
    const int bx = blockIdx.x;
    const int t  = threadIdx.x;

    if (bx < 784) {
        const int b = bx / 392;
        const int rem = bx - b * 392;
        const int uv = rem % 49;
        const int band = rem / 49;           // 0..7
        const int u = uv / 7 - 3, v = uv % 7 - 3;
        const int y0 = band << 3;
        const int lane = t & 63, wv = t >> 6;
        const float4* ftt = reinterpret_cast<const float4*>(ws + WS_FTT)
                          + ((size_t)b << 15);
        const float4* f1t = reinterpret_cast<const float4*>(ws + WS_F1T)
                          + ((size_t)b << 15);

        for (int r = wv; r < 10; r += 4) {
            const int a = y0 - 1 + r;
            const int brow = a + u, bcol = lane + v;
            float s = 0.f;
            if ((unsigned)a < 64u && (unsigned)brow < 64u && (unsigned)bcol < 64u) {
                const float4* pa = ftt + (((a << 6) + lane) << 3);
                const float4* pb = f1t + (((brow << 6) + bcol) << 3);
                float4 acc = {0.f, 0.f, 0.f, 0.f};
                #pragma unroll
                for (int i = 0; i < 8; ++i) {
                    float4 av = pa[i], bv = pb[i];
                    acc.x += av.x * bv.x; acc.y += av.y * bv.y;
                    acc.z += av.z * bv.z; acc.w += av.w * bv.w;
                }
                s = (acc.x + acc.y) + (acc.z + acc.w);
            }
            sbuf[r * 64 + lane] = s;
        }
        __syncthreads();

        float* simb = ws + WS_SIM;
        for (int yl = wv; yl < 8; yl += 4) {
            const int yy = y0 + yl;
            const int x = lane;
            const int cy = yy + u, cx = x + v;
            float dot = 0.f;
            if ((unsigned)cy < 64u && (unsigned)cx < 64u) {
                #pragma unroll
                for (int i = 0; i < 3; ++i) {
                    float rs = sbuf[(yl + i) * 64 + x];
                    if (x > 0)  rs += sbuf[(yl + i) * 64 + x - 1];
                    if (x < 63) rs += sbuf[(yl + i) * 64 + x + 1];
                    dot += rs;
                }
            }
            simb[(size_t)(((b << 12) + (yy << 6) + x) << 6) + uv] = dot;
        }
    } else {
        // ---- rBN role ----
        const int pix = ((bx - 784) << 8) + t;
        const int y = (pix >> 6) & 63, x = pix & 63;
        const float* N = ws + WS_N + (pix & ~4095);   // batch base
        float bn = 0.f;
        #pragma unroll
        for (int i = -1; i <= 1; ++i) {
            int yy = y + i;
            if ((unsigned)yy < 64u) {
                const float* Np = N + (yy << 6);
                #pragma unroll
                for (int j = -1; j <= 1; ++j) {
                    int xx = x + j;
                    if ((unsigned)xx < 64u) bn += Np[xx];
                }
            }
        }
        (ws + WS_RBN)[pix] = 1.0f / fmaxf(sqrtf(bn), EPSF);
    }
}

// ---------------------------------------------------------------------------
// Gather: top-4 over dot*rBN(center), gather via channel-last ftm1, aggregate.
// Half-wave (32 lanes = 32 channels) per pixel; block = 8 pixels (same row).
// ---------------------------------------------------------------------------
__global__ __launch_bounds__(256) void gather_kernel(
    const float* __restrict__ ws, const float* __restrict__ agg_w,
    const float* __restrict__ agg_bp, float* __restrict__ out)
{
    const float* wgt    = ws + WS_WGT;
    const float* simb   = ws + WS_SIM;
    const float* ftm1_t = ws + WS_F1T;
    const float* rBN    = ws + WS_RBN;

    __shared__ float obuf[4][64];
    const int lane = threadIdx.x & 63;
    const int wv = threadIdx.x >> 6;
    const int half = lane >> 5;
    const int c = lane & 31;
    const int pix0 = blockIdx.x << 3;
    const int pix = pix0 + (wv << 1) + half;
    const int b = pix >> 12, y = (pix >> 6) & 63, x = pix & 63;

    // ---- top-4 keys: dot * rBN(center); OOB center stored dot==0 -> key 0 ----
    const float* sp = simb + ((size_t)pix << 6);
    float s0, s1;
    {
        const int d0 = c;
        int cy = y + d0 / 7 - 3, cx = x + d0 % 7 - 3;
        int cyc = min(max(cy, 0), 63), cxc = min(max(cx, 0), 63);
        s0 = sp[d0] * rBN[(b << 12) + (cyc << 6) + cxc];
        const int d1 = c + 32;
        if (d1 < 49) {
            int cy1 = y + d1 / 7 - 3, cx1 = x + d1 % 7 - 3;
            int cy1c = min(max(cy1, 0), 63), cx1c = min(max(cx1, 0), 63);
            s1 = sp[d1] * rBN[(b << 12) + (cy1c << 6) + cx1c];
        } else s1 = -3.0e38f;
    }
    int chosen[4];
    #pragma unroll
    for (int k = 0; k < 4; ++k) {
        float bs; int bi;
        if (s0 >= s1) { bs = s0; bi = c; }
        else          { bs = s1; bi = c + 32; }
        #pragma unroll
        for (int off = 16; off; off >>= 1) {   // stays within the half-wave
            float os = __shfl_xor(bs, off, 64);
            int   oi = __shfl_xor(bi, off, 64);
            if (os > bs || (os == bs && oi < bi)) { bs = os; bi = oi; }
        }
        chosen[k] = bi;
        if (bi == c)           s0 = -3.0e38f;
        else if (bi == c + 32) s1 = -3.0e38f;
    }

    // ---- gather + aggregate ----
    float aw[4];
    aw[0] = agg_w[0]; aw[1] = agg_w[1]; aw[2] = agg_w[2]; aw[3] = agg_w[3];
    const float ab = agg_bp[0];

    int cyv[4], cxv[4]; bool cval[4];
    #pragma unroll
    for (int k = 0; k < 4; ++k) {
        int d = chosen[k];
        int di = d / 7, dj = d - di * 7;
        int cy = y + di - 3, cx = x + dj - 3;
        cval[k] = ((unsigned)cy < 64u) && ((unsigned)cx < 64u);
        cyv[k] = cy; cxv[k] = cx;
    }

    float outc = 0.f;
    const float* wp = wgt + (size_t)pix * 288 + c;   // [j*32 + c]
    #pragma unroll
    for (int pi = 0; pi < 3; ++pi) {
        #pragma unroll
        for (int pj = 0; pj < 3; ++pj) {
            float g = ab;
            #pragma unroll
            for (int k = 0; k < 4; ++k) {
                int row = cyv[k] + pi - 1, col = cxv[k] + pj - 1;
                float vv = 0.f;
                if (cval[k] && (unsigned)row < 64u && (unsigned)col < 64u)
                    vv = ftm1_t[((size_t)((b << 12) + (row << 6) + col) << 5) + c];
                g += aw[k] * vv;
            }
            outc += wp[(pi * 3 + pj) << 5] * g;      // coalesced weight read
        }
    }
    obuf[wv][lane] = outc;
    __syncthreads();

    {
        const int cc = threadIdx.x >> 3;   // 0..31
        const int px = threadIdx.x & 7;    // 0..7
        const float vv = obuf[px >> 1][((px & 1) << 5) + cc];
        const int bb = pix0 >> 12, yy = (pix0 >> 6) & 63, xx0 = pix0 & 63;
        out[((size_t)((bb << 5) + cc) << 12) + (yy << 6) + xx0 + px] = vv;
    }
}

// ---------------------------------------------------------------------------
// Fallback (no workspace): monolithic wave-per-pixel kernel (rounds 1-2).
// ---------------------------------------------------------------------------
__global__ __launch_bounds__(256) void agg_fallback(
    const float* __restrict__ feat_t, const float* __restrict__ feat_tm1,
    const float* __restrict__ agg_w, const float* __restrict__ agg_bp,
    const float* __restrict__ wproj_w, const float* __restrict__ wproj_b,
    float* __restrict__ out)
{
    __shared__ __align__(16) float tile[4][2592];
    __shared__ __align__(16) float qbuf[4][384];
    __shared__ __align__(16) float catb[4][64];

    const int lane = threadIdx.x & 63;
    const int wv   = threadIdx.x >> 6;
    const int pix  = blockIdx.x * 4 + wv;
    const int b = pix >> 12;
    const int y = (pix >> 6) & 63;
    const int x = pix & 63;
    float* tl = tile[wv];
    float* qb = qbuf[wv];

    const float* ftm1_b = feat_tm1 + ((size_t)b << 17);
    const float* ft_b   = feat_t   + ((size_t)b << 17);

    for (int idx = lane; idx < 2592; idx += 64) {
        int c = idx / 81, r = idx - c * 81;
        int ty = r / 9,  tx = r - ty * 9;
        int gy = y - 4 + ty, gx = x - 4 + tx;
        float v = 0.f;
        if ((unsigned)gy < 64u && (unsigned)gx < 64u)
            v = ftm1_b[(c << 12) + (gy << 6) + gx];
        tl[idx] = v;
    }

    float qv[5];
    float qp = 0.f;
    {
        int qn = 0;
        for (int idx = lane; idx < 288; idx += 64) {
            int c = idx / 9, p = idx - c * 9;
            int pi = p / 3, pj = p - pi * 3;
            int gy = y - 1 + pi, gx = x - 1 + pj;
            float v = 0.f;
            if ((unsigned)gy < 64u && (unsigned)gx < 64u)
                v = ft_b[(c << 12) + (gy << 6) + gx];
            qv[qn++] = v;
            qp += v * v;
        }
    }
    #pragma unroll
    for (int off = 32; off; off >>= 1) qp += __shfl_xor(qp, off, 64);
    const float qinv = 1.0f / fmaxf(sqrtf(qp), EPSF);
    {
        int qn = 0;
        for (int idx = lane; idx < 288; idx += 64) {
            int c = idx / 9, p = idx - c * 9;
            qb[c * 12 + p] = qv[qn++] * qinv;
        }
    }
    catb[wv][lane] = (lane < 32)
        ? ft_b[(lane << 12) + (y << 6) + x]
        : ftm1_b[((lane - 32) << 12) + (y << 6) + x];
    __syncthreads();

    float sim;
    {
        const int d = lane;
        const int di = d / 7, dj = d - di * 7;
        const int cy = y + di - 3, cx = x + dj - 3;
        const bool act = d < 49;
        const bool valid = act && ((unsigned)cy < 64u) && ((unsigned)cx < 64u);
        sim = act ? 0.0f : -3.0e38f;
        if (valid) {
            float dot = 0.f, n2 = 0.f;
            const int base = di * 9 + dj;
            for (int c = 0; c < 32; ++c) {
                const float4 qa = *reinterpret_cast<const float4*>(&qb[c * 12]);
                const float4 qd = *reinterpret_cast<const float4*>(&qb[c * 12 + 4]);
                const float  qe = qb[c * 12 + 8];
                const float* tp = &tl[c * 81 + base];
                float k0 = tp[0],  k1 = tp[1],  k2 = tp[2];
                float k3 = tp[9],  k4 = tp[10], k5 = tp[11];
                float k6 = tp[18], k7 = tp[19], k8 = tp[20];
                dot += qa.x*k0 + qa.y*k1 + qa.z*k2 + qa.w*k3
                     + qd.x*k4 + qd.y*k5 + qd.z*k6 + qd.w*k7 + qe*k8;
                n2  += k0*k0 + k1*k1 + k2*k2 + k3*k3 + k4*k4
                     + k5*k5 + k6*k6 + k7*k7 + k8*k8;
            }
            sim = dot / fmaxf(sqrtf(n2), EPSF);
        }
    }

    int chosen[4];
    {
        float s = sim; int si = lane;
        #pragma unroll
        for (int k = 0; k < 4; ++k) {
            float bs = s; int bi = si;
            #pragma unroll
            for (int off = 1; off < 64; off <<= 1) {
                float os = __shfl_xor(bs, off, 64);
                int   oi = __shfl_xor(bi, off, 64);
                if (os > bs || (os == bs && oi < bi)) { bs = os; bi = oi; }
            }
            chosen[k] = bi;
            if (si == bi) s = -3.0e38f;
        }
    }
    __syncthreads();

    const float ab  = agg_bp[0];
    const float aw0 = agg_w[0], aw1 = agg_w[1], aw2 = agg_w[2], aw3 = agg_w[3];
    int  dbase[4];
    bool dvalid[4];
    #pragma unroll
    for (int k = 0; k < 4; ++k) {
        int dk = chosen[k];
        int di = dk / 7, dj = dk - di * 7;
        int cy = y + di - 3, cx = x + dj - 3;
        dvalid[k] = ((unsigned)cy < 64u) && ((unsigned)cx < 64u);
        dbase[k]  = di * 9 + dj;
    }
    for (int o = lane; o < 288; o += 64) {
        int c = o / 9, p = o - c * 9;
        int pi = p / 3, pj = p - pi * 3;
        int off = c * 81 + pi * 9 + pj;
        float v0 = dvalid[0] ? tl[off + dbase[0]] : 0.f;
        float v1 = dvalid[1] ? tl[off + dbase[1]] : 0.f;
        float v2 = dvalid[2] ? tl[off + dbase[2]] : 0.f;
        float v3 = dvalid[3] ? tl[off + dbase[3]] : 0.f;
        float a = ab + aw0 * v0 + aw1 * v1 + aw2 * v2 + aw3 * v3;
        float wg = wproj_b[o];
        const float4* w4  = reinterpret_cast<const float4*>(wproj_w);
        const float4* cb4 = reinterpret_cast<const float4*>(&catb[wv][0]);
        #pragma unroll
        for (int i4 = 0; i4 < 16; ++i4) {
            float4 wv4 = w4[o * 16 + i4];
            float4 cv  = cb4[i4];
            wg += wv4.x*cv.x + wv4.y*cv.y + wv4.z*cv.z + wv4.w*cv.w;
        }
        qb[c * 12 + p] = a * wg;
    }
    __syncthreads();

    if (lane < 32) {
        const float* qq = &qb[lane * 12];
        float sum = (((qq[0]+qq[1]) + (qq[2]+qq[3])) + ((qq[4]+qq[5]) + (qq[6]+qq[7]))) + qq[8];
        out[((size_t)b << 17) + (lane << 12) + (y << 6) + x] = sum;
    }
}

// ---------------------------------------------------------------------------
extern "C" void kernel_launch(void* const* d_in, const int* in_sizes, int n_in,
                              void* d_out, int out_size, void* d_ws, size_t ws_size,
                              hipStream_t stream)
{
    const float* feat_t   = (const float*)d_in[0];
    const float* feat_tm1 = (const float*)d_in[1];
    const float* agg_w    = (const float*)d_in[2];
    const float* agg_b    = (const float*)d_in[3];
    const float* wproj_w  = (const float*)d_in[4];
    const float* wproj_b  = (const float*)d_in[5];
    float* outp = (float*)d_out;

    const size_t need = (size_t)WS_NEED * sizeof(float);
    if (ws_size >= need) {
        float* ws = (float*)d_ws;
        trans_kernel<<<128, 256, 0, stream>>>(feat_t, feat_tm1, ws);
        wgt_kernel<<<512, 256, 0, stream>>>(feat_t, feat_tm1, wproj_w, wproj_b, ws + WS_WGT);
        sim_kernel<<<816, 256, 0, stream>>>(ws);
        gather_kernel<<<NPIX / 8, 256, 0, stream>>>(ws, agg_w, agg_b, outp);
    } else {
        agg_fallback<<<NPIX / 4, 256, 0, stream>>>(feat_t, feat_tm1, agg_w, agg_b,
                                                   wproj_w, wproj_b, outp);
    }
}

// Round 5
// 57.123 us; speedup vs baseline: 1.1427x; 1.1427x over previous
//
#include <hip/hip_runtime.h>

// Problem constants (B=2, C=32, H=W=64, P=3, D=7, K=4)
constexpr int NPIX = 2 * 64 * 64;   // 8192 pixels
constexpr float EPSF = 1e-12f;

// ws layout (floats):
constexpr int WS_WGT = 0;          // 8192*288 [pix][j*32 + c]
constexpr int WS_SIM = 2359296;    // 8192*64  [pix][uv], key = boxdot * rBN(center)
constexpr int WS_F1T = 2883584;    // 8192*32  [pix][c]  channel-last ftm1
constexpr int WS_RBN = 3145728;    // (unused, layout kept)
constexpr int WS_FTT = 3153920;    // 8192*32  [pix][c]  channel-last ft
constexpr int WS_N   = 3416064;    // 8192     per-pixel sum_c ftm1^2
constexpr int WS_NEED = 3424256;

// ---------------------------------------------------------------------------
// Transpose kernel: one block per (b, y) row. Builds channel-last copies of
// ft and ftm1 (coalesced both sides via LDS tile) + per-pixel N = sum_c f1^2.
// ---------------------------------------------------------------------------
__global__ __launch_bounds__(256) void trans_kernel(
    const float* __restrict__ ft, const float* __restrict__ ftm1,
    float* __restrict__ ws)
{
    __shared__ float tile[32][65];
    __shared__ float part[4][64];
    const int t = threadIdx.x;
    const int b = blockIdx.x >> 6;
    const int y = blockIdx.x & 63;
    const int x = t & 63;
    const int cg = t >> 6;               // 0..3
    const int rowoff = (y << 6) + x;
    const float* ftb = ft   + ((size_t)b << 17) + rowoff;
    const float* f1b = ftm1 + ((size_t)b << 17) + rowoff;

    // ---- ft -> ft_t ----
    #pragma unroll
    for (int i = 0; i < 8; ++i)
        tile[cg * 8 + i][x] = ftb[(size_t)(cg * 8 + i) << 12];
    __syncthreads();
    {
        float4* dst = reinterpret_cast<float4*>(ws + WS_FTT)
                    + ((size_t)((b << 12) + (y << 6)) << 3);
        #pragma unroll
        for (int s = 0; s < 2; ++s) {
            int idx = t + s * 256;       // 0..511 = px*8 + chunk
            int px = idx >> 3, ch = (idx & 7) << 2;
            float4 q;
            q.x = tile[ch + 0][px]; q.y = tile[ch + 1][px];
            q.z = tile[ch + 2][px]; q.w = tile[ch + 3][px];
            dst[idx] = q;
        }
    }
    __syncthreads();

    // ---- ftm1 -> f1t (+ N) ----
    float nsum = 0.f;
    #pragma unroll
    for (int i = 0; i < 8; ++i) {
        float v = f1b[(size_t)(cg * 8 + i) << 12];
        tile[cg * 8 + i][x] = v;
        nsum += v * v;
    }
    part[cg][x] = nsum;
    __syncthreads();
    {
        float4* dst = reinterpret_cast<float4*>(ws + WS_F1T)
                    + ((size_t)((b << 12) + (y << 6)) << 3);
        #pragma unroll
        for (int s = 0; s < 2; ++s) {
            int idx = t + s * 256;
            int px = idx >> 3, ch = (idx & 7) << 2;
            float4 q;
            q.x = tile[ch + 0][px]; q.y = tile[ch + 1][px];
            q.z = tile[ch + 2][px]; q.w = tile[ch + 3][px];
            dst[idx] = q;
        }
    }
    if (t < 64) {
        float nn = (part[0][t] + part[1][t]) + (part[2][t] + part[3][t]);
        (ws + WS_N)[(b << 12) + (y << 6) + t] = nn;
    }
}

// ---------------------------------------------------------------------------
// wgt kernel v2: LDS-tiled GEMM. Block = 32 px (one row segment), 256 threads
// = (px 0..31) x (og 0..7). W staged in two 144-row halves (38KB, coalesced);
// cat in 64 registers; W read via conflict-free LDS broadcast.
// ---------------------------------------------------------------------------
__global__ __launch_bounds__(256) void wgt_kernel(
    const float* __restrict__ feat_t, const float* __restrict__ feat_tm1,
    const float* __restrict__ wproj_w, const float* __restrict__ wproj_b,
    float* __restrict__ wgt_ws)
{
    __shared__ float Wl[144 * 68];           // 38.25 KB, 68-float padded rows
    const int t = threadIdx.x;
    const int base = blockIdx.x << 5;        // 32 consecutive pixels, same row
    const int b = base >> 12, y = (base >> 6) & 63, x0 = base & 63;
    const int px = t & 31, og = t >> 5;      // og 0..7

    float cat[64];
    {
        const float* ftb = feat_t   + ((size_t)b << 17) + (y << 6) + x0 + px;
        const float* f1b = feat_tm1 + ((size_t)b << 17) + (y << 6) + x0 + px;
        #pragma unroll
        for (int c = 0; c < 32; ++c) cat[c] = ftb[(size_t)c << 12];
        #pragma unroll
        for (int c = 0; c < 32; ++c) cat[32 + c] = f1b[(size_t)c << 12];
    }
    const float4* w4 = reinterpret_cast<const float4*>(wproj_w);

    for (int half = 0; half < 2; ++half) {
        // stage 144 rows x 64 = 2304 float4, fully coalesced
        {
            const float4* src = w4 + half * 2304;
            #pragma unroll
            for (int s = 0; s < 9; ++s) {
                int f4 = s * 256 + t;            // 0..2303
                int row = f4 >> 4, c4 = f4 & 15;
                float4 wv = src[f4];
                *reinterpret_cast<float4*>(&Wl[row * 68 + (c4 << 2)]) = wv;
            }
        }
        __syncthreads();

        float acc[18];
        #pragma unroll
        for (int j = 0; j < 18; ++j) acc[j] = wproj_b[half * 144 + og * 18 + j];
        #pragma unroll 2
        for (int j = 0; j < 18; ++j) {
            const float* wr = &Wl[(og * 18 + j) * 68];
            float a = acc[j];
            #pragma unroll
            for (int i4 = 0; i4 < 16; ++i4) {
                float4 wv = *reinterpret_cast<const float4*>(&wr[i4 << 2]);
                a += wv.x * cat[i4 * 4]     + wv.y * cat[i4 * 4 + 1]
                   + wv.z * cat[i4 * 4 + 2] + wv.w * cat[i4 * 4 + 3];
            }
            acc[j] = a;
        }
        // o = half*144 + og*18 + j ; logical o = c*9 + jj -> store [pix][jj*32+c]
        #pragma unroll
        for (int j = 0; j < 18; ++j) {
            int o = half * 144 + og * 18 + j;
            int c = o / 9, jj = o - c * 9;
            wgt_ws[(size_t)(base + px) * 288 + jj * 32 + c] = acc[j];
        }
        __syncthreads();
    }
}

// ---------------------------------------------------------------------------
// sim kernel v3: block = (b, uv, 8-row band). Lane = (px, chunk): 8 lanes
// cover one 128B descriptor fully (1x line amplification); 3-level shfl dot.
// Stores key = boxdot * rBN(center) (rBN computed per-block from N in LDS).
// ---------------------------------------------------------------------------
__global__ __launch_bounds__(256) void sim_kernel(float* __restrict__ ws)
{
    __shared__ float sbuf[10][64];
    __shared__ float rbn[14][64];
    __shared__ float nbuf[16][66];
    const int t = threadIdx.x;
    const int bx = blockIdx.x;
    const int b = bx / 392;
    const int rem = bx - b * 392;
    const int uv = rem % 49;
    const int band = rem / 49;           // 0..7
    const int u = uv / 7 - 3, v = uv % 7 - 3;
    const int y0 = band << 3;

    // ---- stage N rows [y0-4, y0+11] into nbuf (zero-padded cols) ----
    {
        const int r = t >> 4;                // 0..15
        const int xq = (t & 15) << 2;        // 0,4,...,60
        const int a = y0 - 4 + r;
        float4 nv = {0.f, 0.f, 0.f, 0.f};
        if ((unsigned)a < 64u)
            nv = *reinterpret_cast<const float4*>(ws + WS_N + (b << 12) + (a << 6) + xq);
        nbuf[r][xq + 1] = nv.x; nbuf[r][xq + 2] = nv.y;
        nbuf[r][xq + 3] = nv.z; nbuf[r][xq + 4] = nv.w;
        if (t < 16) { nbuf[t][0] = 0.f; nbuf[t][65] = 0.f; }
    }
    __syncthreads();

    // ---- rbn rows y0-3 .. y0+10 ----
    for (int idx = t; idx < 14 * 64; idx += 256) {
        int r = idx >> 6, x = idx & 63;
        float bn = 0.f;
        #pragma unroll
        for (int i = 0; i < 3; ++i)
            #pragma unroll
            for (int j = 0; j < 3; ++j)
                bn += nbuf[r + i][x + j];
        rbn[r][x] = 1.0f / fmaxf(sqrtf(bn), EPSF);
    }

    // ---- S rows a = y0-1 .. y0+8 ----
    {
        const float4* ftt4 = reinterpret_cast<const float4*>(ws + WS_FTT);
        const float4* f1t4 = reinterpret_cast<const float4*>(ws + WS_F1T);
        const int ch = t & 7;            // chunk 0..7 (4 channels each)
        const int pxl = t >> 3;          // 0..31
        #pragma unroll
        for (int rr = 0; rr < 10; ++rr) {
            const int a = y0 - 1 + rr;
            const int ar = a + u;
            const bool rowOK = ((unsigned)a < 64u) && ((unsigned)ar < 64u);
            #pragma unroll
            for (int hf = 0; hf < 2; ++hf) {
                const int px = (hf << 5) + pxl;
                const int bc = px + v;
                float part = 0.f;
                if (rowOK && (unsigned)bc < 64u) {
                    float4 av = ftt4[((size_t)((b << 12) + (a  << 6) + px) << 3) + ch];
                    float4 bv = f1t4[((size_t)((b << 12) + (ar << 6) + bc) << 3) + ch];
                    part = av.x * bv.x + av.y * bv.y + av.z * bv.z + av.w * bv.w;
                }
                part += __shfl_xor(part, 1, 64);
                part += __shfl_xor(part, 2, 64);
                part += __shfl_xor(part, 4, 64);
                if (ch == 0) sbuf[rr][px] = part;
            }
        }
    }
    __syncthreads();

    // ---- 3x3 box-sum + rBN multiply + store keys ----
    float* simb = ws + WS_SIM;
    const int lane = t & 63, wvv = t >> 6;
    for (int yl = wvv; yl < 8; yl += 4) {
        const int yy = y0 + yl;
        const int x = lane;
        const int cy = yy + u, cx = x + v;
        float sim = 0.f;
        if ((unsigned)cy < 64u && (unsigned)cx < 64u) {
            float dot = 0.f;
            #pragma unroll
            for (int i = 0; i < 3; ++i) {
                float rs = sbuf[yl + i][x];
                if (x > 0)  rs += sbuf[yl + i][x - 1];
                if (x < 63) rs += sbuf[yl + i][x + 1];
                dot += rs;
            }
            sim = dot * rbn[yl + u + 3][cx];
        }
        simb[(size_t)(((b << 12) + (yy << 6) + x) << 6) + uv] = sim;
    }
}

// ---------------------------------------------------------------------------
// Gather: top-4 over precomputed keys, gather via channel-last ftm1, aggregate.
// Half-wave (32 lanes = 32 channels) per pixel; block = 8 pixels (same row).
// ---------------------------------------------------------------------------
__global__ __launch_bounds__(256) void gather_kernel(
    const float* __restrict__ ws, const float* __restrict__ agg_w,
    const float* __restrict__ agg_bp, float* __restrict__ out)
{
    const float* wgt    = ws + WS_WGT;
    const float* simb   = ws + WS_SIM;
    const float* ftm1_t = ws + WS_F1T;

    __shared__ float obuf[4][64];
    const int lane = threadIdx.x & 63;
    const int wv = threadIdx.x >> 6;
    const int half = lane >> 5;
    const int c = lane & 31;
    const int pix0 = blockIdx.x << 3;
    const int pix = pix0 + (wv << 1) + half;
    const int b = pix >> 12, y = (pix >> 6) & 63, x = pix & 63;

    // ---- top-4 over 49 keys (stable: ties -> lower uv) ----
    const float* sp = simb + ((size_t)pix << 6);
    float s0 = sp[c];
    float s1 = (c + 32 < 49) ? sp[c + 32] : -3.0e38f;
    int chosen[4];
    #pragma unroll
    for (int k = 0; k < 4; ++k) {
        float bs; int bi;
        if (s0 >= s1) { bs = s0; bi = c; }
        else          { bs = s1; bi = c + 32; }
        #pragma unroll
        for (int off = 16; off; off >>= 1) {   // stays within the half-wave
            float os = __shfl_xor(bs, off, 64);
            int   oi = __shfl_xor(bi, off, 64);
            if (os > bs || (os == bs && oi < bi)) { bs = os; bi = oi; }
        }
        chosen[k] = bi;
        if (bi == c)           s0 = -3.0e38f;
        else if (bi == c + 32) s1 = -3.0e38f;
    }

    // ---- gather + aggregate ----
    float aw[4];
    aw[0] = agg_w[0]; aw[1] = agg_w[1]; aw[2] = agg_w[2]; aw[3] = agg_w[3];
    const float ab = agg_bp[0];

    int cyv[4], cxv[4]; bool cval[4];
    #pragma unroll
    for (int k = 0; k < 4; ++k) {
        int d = chosen[k];
        int di = d / 7, dj = d - di * 7;
        int cy = y + di - 3, cx = x + dj - 3;
        cval[k] = ((unsigned)cy < 64u) && ((unsigned)cx < 64u);
        cyv[k] = cy; cxv[k] = cx;
    }

    float outc = 0.f;
    const float* wp = wgt + (size_t)pix * 288 + c;   // [j*32 + c]
    #pragma unroll
    for (int pi = 0; pi < 3; ++pi) {
        #pragma unroll
        for (int pj = 0; pj < 3; ++pj) {
            float g = ab;
            #pragma unroll
            for (int k = 0; k < 4; ++k) {
                int row = cyv[k] + pi - 1, col = cxv[k] + pj - 1;
                float vv = 0.f;
                if (cval[k] && (unsigned)row < 64u && (unsigned)col < 64u)
                    vv = ftm1_t[((size_t)((b << 12) + (row << 6) + col) << 5) + c];
                g += aw[k] * vv;
            }
            outc += wp[(pi * 3 + pj) << 5] * g;      // coalesced weight read
        }
    }
    obuf[wv][lane] = outc;
    __syncthreads();

    {
        const int cc = threadIdx.x >> 3;   // 0..31
        const int px = threadIdx.x & 7;    // 0..7
        const float vv = obuf[px >> 1][((px & 1) << 5) + cc];
        const int bb = pix0 >> 12, yy = (pix0 >> 6) & 63, xx0 = pix0 & 63;
        out[((size_t)((bb << 5) + cc) << 12) + (yy << 6) + xx0 + px] = vv;
    }
}

// ---------------------------------------------------------------------------
// Fallback (no workspace): monolithic wave-per-pixel kernel (rounds 1-2).
// ---------------------------------------------------------------------------
__global__ __launch_bounds__(256) void agg_fallback(
    const float* __restrict__ feat_t, const float* __restrict__ feat_tm1,
    const float* __restrict__ agg_w, const float* __restrict__ agg_bp,
    const float* __restrict__ wproj_w, const float* __restrict__ wproj_b,
    float* __restrict__ out)
{
    __shared__ __align__(16) float tile[4][2592];
    __shared__ __align__(16) float qbuf[4][384];
    __shared__ __align__(16) float catb[4][64];

    const int lane = threadIdx.x & 63;
    const int wv   = threadIdx.x >> 6;
    const int pix  = blockIdx.x * 4 + wv;
    const int b = pix >> 12;
    const int y = (pix >> 6) & 63;
    const int x = pix & 63;
    float* tl = tile[wv];
    float* qb = qbuf[wv];

    const float* ftm1_b = feat_tm1 + ((size_t)b << 17);
    const float* ft_b   = feat_t   + ((size_t)b << 17);

    for (int idx = lane; idx < 2592; idx += 64) {
        int c = idx / 81, r = idx - c * 81;
        int ty = r / 9,  tx = r - ty * 9;
        int gy = y - 4 + ty, gx = x - 4 + tx;
        float v = 0.f;
        if ((unsigned)gy < 64u && (unsigned)gx < 64u)
            v = ftm1_b[(c << 12) + (gy << 6) + gx];
        tl[idx] = v;
    }

    float qv[5];
    float qp = 0.f;
    {
        int qn = 0;
        for (int idx = lane; idx < 288; idx += 64) {
            int c = idx / 9, p = idx - c * 9;
            int pi = p / 3, pj = p - pi * 3;
            int gy = y - 1 + pi, gx = x - 1 + pj;
            float v = 0.f;
            if ((unsigned)gy < 64u && (unsigned)gx < 64u)
                v = ft_b[(c << 12) + (gy << 6) + gx];
            qv[qn++] = v;
            qp += v * v;
        }
    }
    #pragma unroll
    for (int off = 32; off; off >>= 1) qp += __shfl_xor(qp, off, 64);
    const float qinv = 1.0f / fmaxf(sqrtf(qp), EPSF);
    {
        int qn = 0;
        for (int idx = lane; idx < 288; idx += 64) {
            int c = idx / 9, p = idx - c * 9;
            qb[c * 12 + p] = qv[qn++] * qinv;
        }
    }
    catb[wv][lane] = (lane < 32)
        ? ft_b[(lane << 12) + (y << 6) + x]
        : ftm1_b[((lane - 32) << 12) + (y << 6) + x];
    __syncthreads();

    float sim;
    {
        const int d = lane;
        const int di = d / 7, dj = d - di * 7;
        const int cy = y + di - 3, cx = x + dj - 3;
        const bool act = d < 49;
        const bool valid = act && ((unsigned)cy < 64u) && ((unsigned)cx < 64u);
        sim = act ? 0.0f : -3.0e38f;
        if (valid) {
            float dot = 0.f, n2 = 0.f;
            const int base = di * 9 + dj;
            for (int c = 0; c < 32; ++c) {
                const float4 qa = *reinterpret_cast<const float4*>(&qb[c * 12]);
                const float4 qd = *reinterpret_cast<const float4*>(&qb[c * 12 + 4]);
                const float  qe = qb[c * 12 + 8];
                const float* tp = &tl[c * 81 + base];
                float k0 = tp[0],  k1 = tp[1],  k2 = tp[2];
                float k3 = tp[9],  k4 = tp[10], k5 = tp[11];
                float k6 = tp[18], k7 = tp[19], k8 = tp[20];
                dot += qa.x*k0 + qa.y*k1 + qa.z*k2 + qa.w*k3
                     + qd.x*k4 + qd.y*k5 + qd.z*k6 + qd.w*k7 + qe*k8;
                n2  += k0*k0 + k1*k1 + k2*k2 + k3*k3 + k4*k4
                     + k5*k5 + k6*k6 + k7*k7 + k8*k8;
            }
            sim = dot / fmaxf(sqrtf(n2), EPSF);
        }
    }

    int chosen[4];
    {
        float s = sim; int si = lane;
        #pragma unroll
        for (int k = 0; k < 4; ++k) {
            float bs = s; int bi = si;
            #pragma unroll
            for (int off = 1; off < 64; off <<= 1) {
                float os = __shfl_xor(bs, off, 64);
                int   oi = __shfl_xor(bi, off, 64);
                if (os > bs || (os == bs && oi < bi)) { bs = os; bi = oi; }
            }
            chosen[k] = bi;
            if (si == bi) s = -3.0e38f;
        }
    }
    __syncthreads();

    const float ab  = agg_bp[0];
    const float aw0 = agg_w[0], aw1 = agg_w[1], aw2 = agg_w[2], aw3 = agg_w[3];
    int  dbase[4];
    bool dvalid[4];
    #pragma unroll
    for (int k = 0; k < 4; ++k) {
        int dk = chosen[k];
        int di = dk / 7, dj = dk - di * 7;
        int cy = y + di - 3, cx = x + dj - 3;
        dvalid[k] = ((unsigned)cy < 64u) && ((unsigned)cx < 64u);
        dbase[k]  = di * 9 + dj;
    }
    for (int o = lane; o < 288; o += 64) {
        int c = o / 9, p = o - c * 9;
        int pi = p / 3, pj = p - pi * 3;
        int off = c * 81 + pi * 9 + pj;
        float v0 = dvalid[0] ? tl[off + dbase[0]] : 0.f;
        float v1 = dvalid[1] ? tl[off + dbase[1]] : 0.f;
        float v2 = dvalid[2] ? tl[off + dbase[2]] : 0.f;
        float v3 = dvalid[3] ? tl[off + dbase[3]] : 0.f;
        float a = ab + aw0 * v0 + aw1 * v1 + aw2 * v2 + aw3 * v3;
        float wg = wproj_b[o];
        const float4* w4  = reinterpret_cast<const float4*>(wproj_w);
        const float4* cb4 = reinterpret_cast<const float4*>(&catb[wv][0]);
        #pragma unroll
        for (int i4 = 0; i4 < 16; ++i4) {
            float4 wv4 = w4[o * 16 + i4];
            float4 cv  = cb4[i4];
            wg += wv4.x*cv.x + wv4.y*cv.y + wv4.z*cv.z + wv4.w*cv.w;
        }
        qb[c * 12 + p] = a * wg;
    }
    __syncthreads();

    if (lane < 32) {
        const float* qq = &qb[lane * 12];
        float sum = (((qq[0]+qq[1]) + (qq[2]+qq[3])) + ((qq[4]+qq[5]) + (qq[6]+qq[7]))) + qq[8];
        out[((size_t)b << 17) + (lane << 12) + (y << 6) + x] = sum;
    }
}

// ---------------------------------------------------------------------------
extern "C" void kernel_launch(void* const* d_in, const int* in_sizes, int n_in,
                              void* d_out, int out_size, void* d_ws, size_t ws_size,
                              hipStream_t stream)
{
    const float* feat_t   = (const float*)d_in[0];
    const float* feat_tm1 = (const float*)d_in[1];
    const float* agg_w    = (const float*)d_in[2];
    const float* agg_b    = (const float*)d_in[3];
    const float* wproj_w  = (const float*)d_in[4];
    const float* wproj_b  = (const float*)d_in[5];
    float* outp = (float*)d_out;

    const size_t need = (size_t)WS_NEED * sizeof(float);
    if (ws_size >= need) {
        float* ws = (float*)d_ws;
        trans_kernel<<<128, 256, 0, stream>>>(feat_t, feat_tm1, ws);
        wgt_kernel<<<256, 256, 0, stream>>>(feat_t, feat_tm1, wproj_w, wproj_b, ws + WS_WGT);
        sim_kernel<<<784, 256, 0, stream>>>(ws);
        gather_kernel<<<NPIX / 8, 256, 0, stream>>>(ws, agg_w, agg_b, outp);
    } else {
        agg_fallback<<<NPIX / 4, 256, 0, stream>>>(feat_t, feat_tm1, agg_w, agg_b,
                                                   wproj_w, wproj_b, outp);
    }
}

// Round 6
// 39.269 us; speedup vs baseline: 1.6623x; 1.4546x over previous
//
#include <hip/hip_runtime.h>

// Problem constants (B=2, C=32, H=W=64, P=3, D=7, K=4)
constexpr float EPSF = 1e-12f;

// ---------------------------------------------------------------------------
// Monolithic kernel: one block = 16 output pixels (quarter row). All
// intermediates in LDS/registers; no workspace.
//
// LDS float pool layout (48664 B):
//   Wl   @0     : 144 rows x 68            (wgt staging, transient)
//   kw   @0     : 216 pos x 36 c-last      (ftm1 window, overwrites Wl)
//   qw   @7776  : 54 pos x 36 c-last       (ft window)
//   catl @9792  : 16 i4 x 16 px x 4        (concat features at the 16 px)
//   Tb   @10816 : 49 uv x 20               (row-collapsed box-sums T)
//   Nb   @11796 : 216                      (per-pos sum_c ftm1^2)
//   rbnb @12012 : 154 = 7 x 22             (1/max(||patch||,eps))
// ---------------------------------------------------------------------------
__global__ __launch_bounds__(256) void agg_mono(
    const float* __restrict__ ft, const float* __restrict__ f1,
    const float* __restrict__ agg_w, const float* __restrict__ agg_bp,
    const float* __restrict__ wproj_w, const float* __restrict__ wproj_b,
    float* __restrict__ out)
{
    __shared__ __align__(16) float lds[12166];
    __shared__ int chosb[16][4];

    float* Wl   = lds;
    float* kw   = lds;
    float* qw   = lds + 7776;
    float* catl = lds + 9792;
    float* Tb   = lds + 10816;
    float* Nb   = lds + 11796;
    float* rbnb = lds + 12012;

    const int t = threadIdx.x;
    const int pix0 = blockIdx.x << 4;
    const int b  = pix0 >> 12;
    const int y  = (pix0 >> 6) & 63;
    const int x0 = pix0 & 63;

    const float* ftb = ft + ((size_t)b << 17);
    const float* f1b = f1 + ((size_t)b << 17);

    // ---- P0: stage cat (64 ch x 16 px) as float4-chunked [i4][px][4] ----
    #pragma unroll
    for (int s = 0; s < 4; ++s) {
        int idx = (s << 8) + t;                 // 0..1023
        int i = idx >> 4, ppx = idx & 15;
        const float* src = (i < 32) ? ftb : f1b;
        float v = src[((size_t)(i & 31) << 12) + (y << 6) + x0 + ppx];
        catl[((i >> 2) << 6) + (ppx << 2) + (i & 3)] = v;
    }

    // ---- P1: wgt projection. Thread (px, og): 18 outputs o = og*18+j,
    //      kept in registers until P6. W staged in two 144-row LDS halves. ----
    const int px = t & 15;
    const int og = t >> 4;                      // 0..15
    float acc[18];
    const float4* w4 = reinterpret_cast<const float4*>(wproj_w);
    for (int h = 0; h < 2; ++h) {
        __syncthreads();   // h=0: catl ready; h=1: previous compute done
        #pragma unroll
        for (int s = 0; s < 9; ++s) {
            int f4 = (s << 8) + t;              // 0..2303
            int row = f4 >> 4, c4 = f4 & 15;
            *reinterpret_cast<float4*>(&Wl[row * 68 + (c4 << 2)]) = w4[h * 2304 + f4];
        }
        __syncthreads();
        if ((og >> 3) == h) {
            const int ogl = og & 7;
            #pragma unroll
            for (int j = 0; j < 18; ++j) acc[j] = wproj_b[h * 144 + ogl * 18 + j];
            for (int i4 = 0; i4 < 16; ++i4) {
                float4 cv = *reinterpret_cast<const float4*>(&catl[(i4 << 6) + (px << 2)]);
                #pragma unroll
                for (int j = 0; j < 18; ++j) {
                    float4 wv = *reinterpret_cast<const float4*>(
                        &Wl[(ogl * 18 + j) * 68 + (i4 << 2)]);
                    acc[j] += wv.x * cv.x + wv.y * cv.y + wv.z * cv.z + wv.w * cv.w;
                }
            }
        }
    }
    __syncthreads();   // Wl dead -> reuse as kw/qw

    // ---- P2: stage ftm1 window (9x24x32) and ft window (3x18x32), c-last ----
    for (int idx = t; idx < 6912; idx += 256) {
        int c = idx / 216, rem = idx - c * 216;
        int kr = rem / 24, kc = rem - kr * 24;
        int gy = y - 4 + kr, gx = x0 - 4 + kc;
        float v = 0.f;
        if ((unsigned)gy < 64u && (unsigned)gx < 64u)
            v = f1b[((size_t)c << 12) + (gy << 6) + gx];
        kw[rem * 36 + c] = v;
    }
    for (int idx = t; idx < 1728; idx += 256) {
        int c = idx / 54, rem = idx - c * 54;
        int qr = rem / 18, qc = rem - qr * 18;
        int gy = y - 1 + qr, gx = x0 - 1 + qc;
        float v = 0.f;
        if ((unsigned)gy < 64u && (unsigned)gx < 64u)
            v = ftb[((size_t)c << 12) + (gy << 6) + gx];
        qw[rem * 36 + c] = v;
    }
    __syncthreads();

    // ---- P3: N = sum_c ftm1^2 per window pos, then rbn = 1/max(sqrt(box3),eps) ----
    if (t < 216) {
        float s = 0.f;
        #pragma unroll
        for (int c4 = 0; c4 < 8; ++c4) {
            float4 v = *reinterpret_cast<const float4*>(&kw[t * 36 + (c4 << 2)]);
            s += v.x * v.x + v.y * v.y + v.z * v.z + v.w * v.w;
        }
        Nb[t] = s;
    }
    __syncthreads();
    if (t < 154) {
        int cyi = t / 22, cxi = t - cyi * 22;
        int kr = cyi + 1, kc = cxi + 1;
        float bn = 0.f;
        #pragma unroll
        for (int di = -1; di <= 1; ++di)
            #pragma unroll
            for (int dj = -1; dj <= 1; ++dj)
                bn += Nb[(kr + di) * 24 + kc + dj];
        rbnb[t] = 1.0f / fmaxf(sqrtf(bn), EPSF);
    }

    // ---- P4: T[uv][xx] = sum_r S(r,xx,uv). 8-lane c-groups, shfl reduce. ----
    {
        const int g = t >> 3, c4 = t & 7;
        #pragma unroll
        for (int pr = 0; pr < 4; ++pr) {
            int p = (pr << 5) + g;              // (xx,u) pair id
            if (p < 126) {
                int u = p / 18, xx = p - u * 18;
                float av[7] = {0.f, 0.f, 0.f, 0.f, 0.f, 0.f, 0.f};
                #pragma unroll
                for (int r = 0; r < 3; ++r) {
                    float4 qv = *reinterpret_cast<const float4*>(
                        &qw[(r * 18 + xx) * 36 + (c4 << 2)]);
                    #pragma unroll
                    for (int v = 0; v < 7; ++v) {
                        float4 kv = *reinterpret_cast<const float4*>(
                            &kw[((r + u) * 24 + xx + v) * 36 + (c4 << 2)]);
                        av[v] += qv.x * kv.x + qv.y * kv.y + qv.z * kv.z + qv.w * kv.w;
                    }
                }
                #pragma unroll
                for (int v = 0; v < 7; ++v) {
                    float s = av[v];
                    s += __shfl_xor(s, 1, 64);
                    s += __shfl_xor(s, 2, 64);
                    s += __shfl_xor(s, 4, 64);
                    if (c4 == 0) Tb[(u * 7 + v) * 20 + xx] = s;
                }
            }
        }
    }
    __syncthreads();

    // ---- P5: keys = box3(T)*rbn (0 if center OOB); stable top-4 per px ----
    {
        const int lane = t & 63;
        const int wvv = t >> 6;
        const int hf = lane >> 5;
        const int c = lane & 31;
        #pragma unroll
        for (int rnd = 0; rnd < 2; ++rnd) {
            const int ppx = (wvv << 2) + (rnd << 1) + hf;
            float s0 = 0.f, s1;
            {
                int u = c / 7, v = c - u * 7;
                int cy = y + u - 3, cx = x0 + ppx + v - 3;
                if ((unsigned)cy < 64u && (unsigned)cx < 64u) {
                    float dot = Tb[c * 20 + ppx] + Tb[c * 20 + ppx + 1]
                              + Tb[c * 20 + ppx + 2];
                    s0 = dot * rbnb[u * 22 + ppx + v];
                }
            }
            if (c < 17) {
                int d = c + 32;
                int u = d / 7, v = d - u * 7;
                int cy = y + u - 3, cx = x0 + ppx + v - 3;
                s1 = 0.f;
                if ((unsigned)cy < 64u && (unsigned)cx < 64u) {
                    float dot = Tb[d * 20 + ppx] + Tb[d * 20 + ppx + 1]
                              + Tb[d * 20 + ppx + 2];
                    s1 = dot * rbnb[u * 22 + ppx + v];
                }
            } else s1 = -3.0e38f;
            #pragma unroll
            for (int k = 0; k < 4; ++k) {
                float bs; int bi;
                if (s0 >= s1) { bs = s0; bi = c; }
                else          { bs = s1; bi = c + 32; }
                #pragma unroll
                for (int off = 16; off; off >>= 1) {   // within half-wave
                    float os = __shfl_xor(bs, off, 64);
                    int   oi = __shfl_xor(bi, off, 64);
                    if (os > bs || (os == bs && oi < bi)) { bs = os; bi = oi; }
                }
                if (c == 0) chosb[ppx][k] = bi;
                if (bi == c)           s0 = -3.0e38f;
                else if (bi == c + 32) s1 = -3.0e38f;
            }
        }
    }
    __syncthreads();

    // ---- P6: gather top-4 patches from kw, aggregate, multiply wgt, store ----
    {
        const float ab = agg_bp[0];
        float awv[4];
        #pragma unroll
        for (int k = 0; k < 4; ++k) awv[k] = agg_w[k];
        int uo[4], vo[4]; bool cval[4];
        #pragma unroll
        for (int k = 0; k < 4; ++k) {
            int d = chosb[px][k];
            int u = d / 7, v = d - u * 7;
            int cy = y + u - 3, cx = x0 + px + v - 3;
            cval[k] = ((unsigned)cy < 64u) && ((unsigned)cx < 64u);
            uo[k] = u; vo[k] = v;
        }
        #pragma unroll
        for (int cl = 0; cl < 2; ++cl) {
            const int c = (og << 1) + cl;
            float outv = 0.f;
            #pragma unroll
            for (int j = 0; j < 9; ++j) {
                int pi = j / 3, pj = j - pi * 3;
                float gacc = ab;
                #pragma unroll
                for (int k = 0; k < 4; ++k) {
                    float vv = 0.f;
                    if (cval[k])
                        vv = kw[((uo[k] + pi) * 24 + px + vo[k] + pj) * 36 + c];
                    gacc += awv[k] * vv;
                }
                outv += acc[cl * 9 + j] * gacc;
            }
            out[((size_t)((b << 5) + c) << 12) + (y << 6) + x0 + px] = outv;
        }
    }
}

// ---------------------------------------------------------------------------
extern "C" void kernel_launch(void* const* d_in, const int* in_sizes, int n_in,
                              void* d_out, int out_size, void* d_ws, size_t ws_size,
                              hipStream_t stream)
{
    const float* feat_t   = (const float*)d_in[0];
    const float* feat_tm1 = (const float*)d_in[1];
    const float* agg_w    = (const float*)d_in[2];
    const float* agg_b    = (const float*)d_in[3];
    const float* wproj_w  = (const float*)d_in[4];
    const float* wproj_b  = (const float*)d_in[5];
    float* outp = (float*)d_out;
    (void)d_ws; (void)ws_size;

    agg_mono<<<512, 256, 0, stream>>>(feat_t, feat_tm1, agg_w, agg_b,
                                      wproj_w, wproj_b, outp);
}

// Round 7
// 29.678 us; speedup vs baseline: 2.1995x; 1.3232x over previous
//
#include <hip/hip_runtime.h>

// Problem constants (B=2, C=32, H=W=64, P=3, D=7, K=4)
constexpr float EPSF = 1e-12f;

// ---------------------------------------------------------------------------
// Monolithic kernel v2: one block = 16 output pixels, 512 threads (8 waves).
// All intermediates in LDS/registers; no workspace.
//
// LDS float pool layout (48664 B):
//   Wl   @0     : 144 rows x 68            (wgt staging, transient)
//   kw   @0     : 216 pos x 36 c-last      (ftm1 window, overwrites Wl)
//   qw   @7776  : 54 pos x 36 c-last       (ft window, overlays Wl tail)
//   catl @9792  : 16 i4 x 16 px x 4        (concat features at the 16 px)
//   Tb   @10816 : 49 uv x 20               (row-collapsed box-sums T)
//   Nb   @11796 : 216                      (per-pos sum_c ftm1^2)
//   rbnb @12012 : 154 = 7 x 22             (1/max(||patch||,eps))
// ---------------------------------------------------------------------------
__global__ __launch_bounds__(512) void agg_mono(
    const float* __restrict__ ft, const float* __restrict__ f1,
    const float* __restrict__ agg_w, const float* __restrict__ agg_bp,
    const float* __restrict__ wproj_w, const float* __restrict__ wproj_b,
    float* __restrict__ out)
{
    __shared__ __align__(16) float lds[12166];
    __shared__ int chosb[16][4];

    float* Wl   = lds;
    float* kw   = lds;
    float* qw   = lds + 7776;
    float* catl = lds + 9792;
    float* Tb   = lds + 10816;
    float* Nb   = lds + 11796;
    float* rbnb = lds + 12012;

    const int t = threadIdx.x;
    const int pix0 = blockIdx.x << 4;
    const int b  = pix0 >> 12;
    const int y  = (pix0 >> 6) & 63;
    const int x0 = pix0 & 63;

    const float* ftb = ft + ((size_t)b << 17);
    const float* f1b = f1 + ((size_t)b << 17);

    // ---- P0: stage cat (64 ch x 16 px) as float4-chunked [i4][px][4] ----
    #pragma unroll
    for (int s = 0; s < 2; ++s) {
        int idx = (s << 9) + t;                 // 0..1023
        int i = idx >> 4, ppx = idx & 15;
        const float* src = (i < 32) ? ftb : f1b;
        float v = src[((size_t)(i & 31) << 12) + (y << 6) + x0 + ppx];
        catl[((i >> 2) << 6) + (ppx << 2) + (i & 3)] = v;
    }

    // ---- T14: issue window loads early into registers (written to LDS
    //      after P1, since kw/qw overlay Wl). Latency hides under P1. ----
    float stgK[14];
    #pragma unroll
    for (int s = 0; s < 14; ++s) {
        int idx = (s << 9) + t;
        if (idx < 6912) {
            int c = idx / 216, rem = idx - c * 216;
            int kr = rem / 24, kc = rem - kr * 24;
            int gy = y - 4 + kr, gx = x0 - 4 + kc;
            stgK[s] = ((unsigned)gy < 64u && (unsigned)gx < 64u)
                    ? f1b[((size_t)c << 12) + (gy << 6) + gx] : 0.f;
        }
    }
    float stgQ[4];
    #pragma unroll
    for (int s = 0; s < 4; ++s) {
        int idx = (s << 9) + t;
        if (idx < 1728) {
            int c = idx / 54, rem = idx - c * 54;
            int qr = rem / 18, qc = rem - qr * 18;
            int gy = y - 1 + qr, gx = x0 - 1 + qc;
            stgQ[s] = ((unsigned)gy < 64u && (unsigned)gx < 64u)
                    ? ftb[((size_t)c << 12) + (gy << 6) + gx] : 0.f;
        }
    }

    // ---- P1: wgt projection. Thread (px = t&15, ogl = t>>4 in 0..31)
    //      computes acc[j] = wgt[ogl*9 + j] for its channel c = ogl. ----
    const int px  = t & 15;
    const int ogl = t >> 4;                     // 0..31 = channel
    float acc[9];
    const float4* w4 = reinterpret_cast<const float4*>(wproj_w);
    for (int h = 0; h < 2; ++h) {
        __syncthreads();   // h=0: catl ready; h=1: previous compute done
        #pragma unroll
        for (int s = 0; s < 5; ++s) {
            int f4 = (s << 9) + t;              // 0..2303
            if (f4 < 2304) {
                int row = f4 >> 4, c4 = f4 & 15;
                *reinterpret_cast<float4*>(&Wl[row * 68 + (c4 << 2)]) = w4[h * 2304 + f4];
            }
        }
        __syncthreads();
        if ((ogl >> 4) == h) {
            const int olg = ogl & 15;
            #pragma unroll
            for (int j = 0; j < 9; ++j) acc[j] = wproj_b[h * 144 + olg * 9 + j];
            for (int i4 = 0; i4 < 16; ++i4) {
                float4 cv = *reinterpret_cast<const float4*>(&catl[(i4 << 6) + (px << 2)]);
                #pragma unroll
                for (int j = 0; j < 9; ++j) {
                    float4 wv = *reinterpret_cast<const float4*>(
                        &Wl[(olg * 9 + j) * 68 + (i4 << 2)]);
                    acc[j] += wv.x * cv.x + wv.y * cv.y + wv.z * cv.z + wv.w * cv.w;
                }
            }
        }
    }
    __syncthreads();   // Wl dead -> kw/qw writes may begin

    // ---- P2: write staged ftm1 window (9x24x32) and ft window (3x18x32) ----
    #pragma unroll
    for (int s = 0; s < 14; ++s) {
        int idx = (s << 9) + t;
        if (idx < 6912) {
            int c = idx / 216, rem = idx - c * 216;
            kw[rem * 36 + c] = stgK[s];
        }
    }
    #pragma unroll
    for (int s = 0; s < 4; ++s) {
        int idx = (s << 9) + t;
        if (idx < 1728) {
            int c = idx / 54, rem = idx - c * 54;
            qw[rem * 36 + c] = stgQ[s];
        }
    }
    __syncthreads();

    // ---- P3: N = sum_c ftm1^2 per window pos; rbn = 1/max(sqrt(box3),eps) ----
    if (t < 216) {
        float s = 0.f;
        #pragma unroll
        for (int c4 = 0; c4 < 8; ++c4) {
            float4 v = *reinterpret_cast<const float4*>(&kw[t * 36 + (c4 << 2)]);
            s += v.x * v.x + v.y * v.y + v.z * v.z + v.w * v.w;
        }
        Nb[t] = s;
    }
    __syncthreads();
    if (t < 154) {
        int cyi = t / 22, cxi = t - cyi * 22;
        int kr = cyi + 1, kc = cxi + 1;
        float bn = 0.f;
        #pragma unroll
        for (int di = -1; di <= 1; ++di)
            #pragma unroll
            for (int dj = -1; dj <= 1; ++dj)
                bn += Nb[(kr + di) * 24 + kc + dj];
        rbnb[t] = 1.0f / fmaxf(sqrtf(bn), EPSF);
    }

    // ---- P4: T[uv][xx] = sum_r S(r,xx,uv). 8-lane c-groups, shfl reduce. ----
    {
        const int g = t >> 3, c4 = t & 7;       // g 0..63
        #pragma unroll
        for (int pr = 0; pr < 2; ++pr) {
            int p = (pr << 6) + g;              // (xx,u) pair id
            if (p < 126) {
                int u = p / 18, xx = p - u * 18;
                float av[7] = {0.f, 0.f, 0.f, 0.f, 0.f, 0.f, 0.f};
                #pragma unroll
                for (int r = 0; r < 3; ++r) {
                    float4 qv = *reinterpret_cast<const float4*>(
                        &qw[(r * 18 + xx) * 36 + (c4 << 2)]);
                    #pragma unroll
                    for (int v = 0; v < 7; ++v) {
                        float4 kv = *reinterpret_cast<const float4*>(
                            &kw[((r + u) * 24 + xx + v) * 36 + (c4 << 2)]);
                        av[v] += qv.x * kv.x + qv.y * kv.y + qv.z * kv.z + qv.w * kv.w;
                    }
                }
                #pragma unroll
                for (int v = 0; v < 7; ++v) {
                    float s = av[v];
                    s += __shfl_xor(s, 1, 64);
                    s += __shfl_xor(s, 2, 64);
                    s += __shfl_xor(s, 4, 64);
                    if (c4 == 0) Tb[(u * 7 + v) * 20 + xx] = s;
                }
            }
        }
    }
    __syncthreads();

    // ---- P5: keys = box3(T)*rbn (0 if center OOB); stable top-4 per px ----
    {
        const int lane = t & 63;
        const int wvv = t >> 6;                 // 0..7
        const int hf = lane >> 5;
        const int c = lane & 31;
        const int ppx = (wvv << 1) + hf;        // 0..15, one round
        float s0 = 0.f, s1;
        {
            int u = c / 7, v = c - u * 7;
            int cy = y + u - 3, cx = x0 + ppx + v - 3;
            if ((unsigned)cy < 64u && (unsigned)cx < 64u) {
                float dot = Tb[c * 20 + ppx] + Tb[c * 20 + ppx + 1]
                          + Tb[c * 20 + ppx + 2];
                s0 = dot * rbnb[u * 22 + ppx + v];
            }
        }
        if (c < 17) {
            int d = c + 32;
            int u = d / 7, v = d - u * 7;
            int cy = y + u - 3, cx = x0 + ppx + v - 3;
            s1 = 0.f;
            if ((unsigned)cy < 64u && (unsigned)cx < 64u) {
                float dot = Tb[d * 20 + ppx] + Tb[d * 20 + ppx + 1]
                          + Tb[d * 20 + ppx + 2];
                s1 = dot * rbnb[u * 22 + ppx + v];
            }
        } else s1 = -3.0e38f;
        #pragma unroll
        for (int k = 0; k < 4; ++k) {
            float bs; int bi;
            if (s0 >= s1) { bs = s0; bi = c; }
            else          { bs = s1; bi = c + 32; }
            #pragma unroll
            for (int off = 16; off; off >>= 1) {   // within half-wave
                float os = __shfl_xor(bs, off, 64);
                int   oi = __shfl_xor(bi, off, 64);
                if (os > bs || (os == bs && oi < bi)) { bs = os; bi = oi; }
            }
            if (c == 0) chosb[ppx][k] = bi;
            if (bi == c)           s0 = -3.0e38f;
            else if (bi == c + 32) s1 = -3.0e38f;
        }
    }
    __syncthreads();

    // ---- P6: gather top-4 patches from kw, aggregate, multiply wgt, store.
    //      Thread (px, ogl): channel c = ogl, weights acc[9]. ----
    {
        const float ab = agg_bp[0];
        float awv[4];
        #pragma unroll
        for (int k = 0; k < 4; ++k) awv[k] = agg_w[k];
        int uo[4], vo[4]; bool cval[4];
        #pragma unroll
        for (int k = 0; k < 4; ++k) {
            int d = chosb[px][k];
            int u = d / 7, v = d - u * 7;
            int cy = y + u - 3, cx = x0 + px + v - 3;
            cval[k] = ((unsigned)cy < 64u) && ((unsigned)cx < 64u);
            uo[k] = u; vo[k] = v;
        }
        const int c = ogl;
        float outv = 0.f;
        #pragma unroll
        for (int j = 0; j < 9; ++j) {
            int pi = j / 3, pj = j - pi * 3;
            float gacc = ab;
            #pragma unroll
            for (int k = 0; k < 4; ++k) {
                float vv = cval[k]
                    ? kw[((uo[k] + pi) * 24 + px + vo[k] + pj) * 36 + c] : 0.f;
                gacc += awv[k] * vv;
            }
            outv += acc[j] * gacc;
        }
        out[((size_t)((b << 5) + c) << 12) + (y << 6) + x0 + px] = outv;
    }
}

// ---------------------------------------------------------------------------
extern "C" void kernel_launch(void* const* d_in, const int* in_sizes, int n_in,
                              void* d_out, int out_size, void* d_ws, size_t ws_size,
                              hipStream_t stream)
{
    const float* feat_t   = (const float*)d_in[0];
    const float* feat_tm1 = (const float*)d_in[1];
    const float* agg_w    = (const float*)d_in[2];
    const float* agg_b    = (const float*)d_in[3];
    const float* wproj_w  = (const float*)d_in[4];
    const float* wproj_b  = (const float*)d_in[5];
    float* outp = (float*)d_out;
    (void)d_ws; (void)ws_size;

    agg_mono<<<512, 512, 0, stream>>>(feat_t, feat_tm1, agg_w, agg_b,
                                      wproj_w, wproj_b, outp);
}

// Round 8
// 22.376 us; speedup vs baseline: 2.9172x; 1.3263x over previous
//
#include <hip/hip_runtime.h>

// Problem constants (B=2, C=32, H=W=64, P=3, D=7, K=4)
constexpr float EPSF = 1e-12f;

using short8 = __attribute__((ext_vector_type(8))) short;
using f32x4  = __attribute__((ext_vector_type(4))) float;

__device__ __forceinline__ unsigned short f2bf(float f) {
    unsigned int u = __float_as_uint(f);
    u += 0x7fffu + ((u >> 16) & 1u);        // round-to-nearest-even
    return (unsigned short)(u >> 16);
}

// ---------------------------------------------------------------------------
// Monolithic kernel v3: block = 16 output pixels, 512 threads (8 waves).
// wgt GEMM (288x64 @ 64x16) on the matrix pipe (bf16 MFMA, fp32 accum);
// similarity/top-k path stays fp32. No workspace.
//
// LDS float pool (65016 B) + chosb:
//   qw   @0     : 54 pos x 36   (ft window, c-last)          [born P2]
//   kw   @1944  : 216 pos x 36  (ftm1 window, c-last)        [born P2]
//   Wb   @0     : bf16[18][8][16][8] = 36864 B  (W staging)  [dead before P2]
//   wgtl @9720  : 16 px x 292   (wgt, f32)                   [born MFMA]
//   Bb   @14392 : bf16[8][16][8] (cat, b-frags)              [born P0]
//   Tb   @14904 : 49 uv x 20    (row-collapsed box-sums)
//   Nb   @15884 : 216           (sum_c ftm1^2)
//   rbnb @16100 : 7 x 22        (1/max(||patch||,eps))
// ---------------------------------------------------------------------------
__global__ __launch_bounds__(512, 4) void agg_mono(
    const float* __restrict__ ft, const float* __restrict__ f1,
    const float* __restrict__ agg_w, const float* __restrict__ agg_bp,
    const float* __restrict__ wproj_w, const float* __restrict__ wproj_b,
    float* __restrict__ out)
{
    __shared__ __align__(16) float pool[16254];
    __shared__ int chosb[16][4];

    float* qw   = pool;                  // [54][36]
    float* kw   = pool + 1944;           // [216][36]
    float* wgtl = pool + 9720;           // [16][292]
    float* Tb   = pool + 14904;          // [49][20]
    float* Nb   = pool + 15884;          // [216]
    float* rbnb = pool + 16100;          // [7][22]
    unsigned short* Wb = reinterpret_cast<unsigned short*>(pool);          // [18][8][16][8]
    unsigned short* Bb = reinterpret_cast<unsigned short*>(pool + 14392);  // [8][16][8]

    const int t = threadIdx.x;
    const int pix0 = blockIdx.x << 4;
    const int b  = pix0 >> 12;
    const int y  = (pix0 >> 6) & 63;
    const int x0 = pix0 & 63;

    const float* ftb = ft + ((size_t)b << 17);
    const float* f1b = f1 + ((size_t)b << 17);

    // ---- T14: issue window loads early into registers (LDS write in P2) ----
    float stgK[14];
    #pragma unroll
    for (int s = 0; s < 14; ++s) {
        int idx = (s << 9) + t;
        if (idx < 6912) {
            int c = idx / 216, rem = idx - c * 216;
            int kr = rem / 24, kc = rem - kr * 24;
            int gy = y - 4 + kr, gx = x0 - 4 + kc;
            stgK[s] = ((unsigned)gy < 64u && (unsigned)gx < 64u)
                    ? f1b[((size_t)c << 12) + (gy << 6) + gx] : 0.f;
        }
    }
    float stgQ[4];
    #pragma unroll
    for (int s = 0; s < 4; ++s) {
        int idx = (s << 9) + t;
        if (idx < 1728) {
            int c = idx / 54, rem = idx - c * 54;
            int qr = rem / 18, qc = rem - qr * 18;
            int gy = y - 1 + qr, gx = x0 - 1 + qc;
            stgQ[s] = ((unsigned)gy < 64u && (unsigned)gx < 64u)
                    ? ftb[((size_t)c << 12) + (gy << 6) + gx] : 0.f;
        }
    }

    // ---- P0: stage cat as bf16 B-fragments Bb[kg][px][8] ----
    #pragma unroll
    for (int s = 0; s < 2; ++s) {
        int idx = (s << 9) + t;              // 0..1023 = i*16 + px
        int i = idx >> 4, ppx = idx & 15;
        const float* src = (i < 32) ? ftb : f1b;
        float v = src[((size_t)(i & 31) << 12) + (y << 6) + x0 + ppx];
        Bb[(((i >> 3) << 4) + ppx) * 8 + (i & 7)] = f2bf(v);
    }

    // ---- P0b: stage W as bf16 A-tiles Wb[tt][kg][row][8] ----
    {
        const float4* w4g = reinterpret_cast<const float4*>(wproj_w);
        #pragma unroll
        for (int s = 0; s < 9; ++s) {
            int f4 = (s << 9) + t;           // 0..4607
            float4 wv = w4g[f4];
            int o = f4 >> 4, k4 = f4 & 15;
            int off = ((((o >> 4) << 3) + (k4 >> 1)) * 16 + (o & 15)) * 8
                    + ((k4 & 1) << 2);
            ushort4 bv;
            bv.x = f2bf(wv.x); bv.y = f2bf(wv.y);
            bv.z = f2bf(wv.z); bv.w = f2bf(wv.w);
            *reinterpret_cast<ushort4*>(&Wb[off]) = bv;
        }
    }
    __syncthreads();

    // ---- P1: wgt GEMM on matrix pipe. Wave w: o-tiles {w, w+8, (w+16 if w<2)}.
    //      D[row=o_local][col=px]: row=(lane>>4)*4+reg, col=lane&15 (m89). ----
    {
        const int lane = t & 63;
        const int wv8 = t >> 6;
        const int lr = lane & 15;
        const int lg = lane >> 4;
        short8 bf0 = *reinterpret_cast<const short8*>(&Bb[(lg * 16 + lr) * 8]);
        short8 bf1 = *reinterpret_cast<const short8*>(&Bb[((4 + lg) * 16 + lr) * 8]);
        #pragma unroll
        for (int ti = 0; ti < 3; ++ti) {
            if (ti == 2 && wv8 >= 2) break;
            const int tt = (ti == 0) ? wv8 : (ti == 1 ? wv8 + 8 : wv8 + 16);
            const float4 bias = *reinterpret_cast<const float4*>(
                wproj_b + tt * 16 + lg * 4);
            f32x4 acc;
            acc[0] = bias.x; acc[1] = bias.y; acc[2] = bias.z; acc[3] = bias.w;
            short8 a0 = *reinterpret_cast<const short8*>(
                &Wb[((tt * 8 + lg) * 16 + lr) * 8]);
            short8 a1 = *reinterpret_cast<const short8*>(
                &Wb[((tt * 8 + 4 + lg) * 16 + lr) * 8]);
            acc = __builtin_amdgcn_mfma_f32_16x16x32_bf16(a0, bf0, acc, 0, 0, 0);
            acc = __builtin_amdgcn_mfma_f32_16x16x32_bf16(a1, bf1, acc, 0, 0, 0);
            *reinterpret_cast<f32x4*>(&wgtl[lr * 292 + tt * 16 + lg * 4]) = acc;
        }
    }
    __syncthreads();   // Wb dead -> kw/qw writes may begin

    // ---- P2: write staged ftm1 window (9x24x32) and ft window (3x18x32) ----
    #pragma unroll
    for (int s = 0; s < 14; ++s) {
        int idx = (s << 9) + t;
        if (idx < 6912) {
            int c = idx / 216, rem = idx - c * 216;
            kw[rem * 36 + c] = stgK[s];
        }
    }
    #pragma unroll
    for (int s = 0; s < 4; ++s) {
        int idx = (s << 9) + t;
        if (idx < 1728) {
            int c = idx / 54, rem = idx - c * 54;
            qw[rem * 36 + c] = stgQ[s];
        }
    }
    __syncthreads();

    // ---- P3: N = sum_c ftm1^2 per window pos; rbn = 1/max(sqrt(box3),eps) ----
    if (t < 216) {
        float s = 0.f;
        #pragma unroll
        for (int c4 = 0; c4 < 8; ++c4) {
            float4 v = *reinterpret_cast<const float4*>(&kw[t * 36 + (c4 << 2)]);
            s += v.x * v.x + v.y * v.y + v.z * v.z + v.w * v.w;
        }
        Nb[t] = s;
    }
    __syncthreads();
    if (t < 154) {
        int cyi = t / 22, cxi = t - cyi * 22;
        int kr = cyi + 1, kc = cxi + 1;
        float bn = 0.f;
        #pragma unroll
        for (int di = -1; di <= 1; ++di)
            #pragma unroll
            for (int dj = -1; dj <= 1; ++dj)
                bn += Nb[(kr + di) * 24 + kc + dj];
        rbnb[t] = 1.0f / fmaxf(sqrtf(bn), EPSF);
    }

    // ---- P4: T[uv][xx] = sum_r S(r,xx,uv). 8-lane c-groups, shfl reduce. ----
    {
        const int g = t >> 3, c4 = t & 7;       // g 0..63
        #pragma unroll
        for (int pr = 0; pr < 2; ++pr) {
            int p = (pr << 6) + g;              // (xx,u) pair id
            if (p < 126) {
                int u = p / 18, xx = p - u * 18;
                float av[7] = {0.f, 0.f, 0.f, 0.f, 0.f, 0.f, 0.f};
                #pragma unroll
                for (int r = 0; r < 3; ++r) {
                    float4 qv = *reinterpret_cast<const float4*>(
                        &qw[(r * 18 + xx) * 36 + (c4 << 2)]);
                    #pragma unroll
                    for (int v = 0; v < 7; ++v) {
                        float4 kv = *reinterpret_cast<const float4*>(
                            &kw[((r + u) * 24 + xx + v) * 36 + (c4 << 2)]);
                        av[v] += qv.x * kv.x + qv.y * kv.y + qv.z * kv.z + qv.w * kv.w;
                    }
                }
                #pragma unroll
                for (int v = 0; v < 7; ++v) {
                    float s = av[v];
                    s += __shfl_xor(s, 1, 64);
                    s += __shfl_xor(s, 2, 64);
                    s += __shfl_xor(s, 4, 64);
                    if (c4 == 0) Tb[(u * 7 + v) * 20 + xx] = s;
                }
            }
        }
    }
    __syncthreads();

    // ---- P5: keys = box3(T)*rbn (0 if center OOB); stable top-4 per px ----
    {
        const int lane = t & 63;
        const int wvv = t >> 6;                 // 0..7
        const int hf = lane >> 5;
        const int c = lane & 31;
        const int ppx = (wvv << 1) + hf;        // 0..15
        float s0 = 0.f, s1;
        {
            int u = c / 7, v = c - u * 7;
            int cy = y + u - 3, cx = x0 + ppx + v - 3;
            if ((unsigned)cy < 64u && (unsigned)cx < 64u) {
                float dot = Tb[c * 20 + ppx] + Tb[c * 20 + ppx + 1]
                          + Tb[c * 20 + ppx + 2];
                s0 = dot * rbnb[u * 22 + ppx + v];
            }
        }
        if (c < 17) {
            int d = c + 32;
            int u = d / 7, v = d - u * 7;
            int cy = y + u - 3, cx = x0 + ppx + v - 3;
            s1 = 0.f;
            if ((unsigned)cy < 64u && (unsigned)cx < 64u) {
                float dot = Tb[d * 20 + ppx] + Tb[d * 20 + ppx + 1]
                          + Tb[d * 20 + ppx + 2];
                s1 = dot * rbnb[u * 22 + ppx + v];
            }
        } else s1 = -3.0e38f;
        #pragma unroll
        for (int k = 0; k < 4; ++k) {
            float bs; int bi;
            if (s0 >= s1) { bs = s0; bi = c; }
            else          { bs = s1; bi = c + 32; }
            #pragma unroll
            for (int off = 16; off; off >>= 1) {   // within half-wave
                float os = __shfl_xor(bs, off, 64);
                int   oi = __shfl_xor(bi, off, 64);
                if (os > bs || (os == bs && oi < bi)) { bs = os; bi = oi; }
            }
            if (c == 0) chosb[ppx][k] = bi;
            if (bi == c)           s0 = -3.0e38f;
            else if (bi == c + 32) s1 = -3.0e38f;
        }
    }
    __syncthreads();

    // ---- P6: gather top-4 patches from kw, aggregate, multiply wgt, store.
    //      Thread (px = t&15, c = t>>4). ----
    {
        const int px = t & 15;
        const int c  = t >> 4;                  // 0..31 = channel
        const float ab = agg_bp[0];
        float awv[4];
        #pragma unroll
        for (int k = 0; k < 4; ++k) awv[k] = agg_w[k];
        int uo[4], vo[4]; bool cval[4];
        #pragma unroll
        for (int k = 0; k < 4; ++k) {
            int d = chosb[px][k];
            int u = d / 7, v = d - u * 7;
            int cy = y + u - 3, cx = x0 + px + v - 3;
            cval[k] = ((unsigned)cy < 64u) && ((unsigned)cx < 64u);
            uo[k] = u; vo[k] = v;
        }
        float outv = 0.f;
        #pragma unroll
        for (int j = 0; j < 9; ++j) {
            int pi = j / 3, pj = j - pi * 3;
            float gacc = ab;
            #pragma unroll
            for (int k = 0; k < 4; ++k) {
                float vv = cval[k]
                    ? kw[((uo[k] + pi) * 24 + px + vo[k] + pj) * 36 + c] : 0.f;
                gacc += awv[k] * vv;
            }
            outv += wgtl[px * 292 + c * 9 + j] * gacc;
        }
        out[((size_t)((b << 5) + c) << 12) + (y << 6) + x0 + px] = outv;
    }
}

// ---------------------------------------------------------------------------
extern "C" void kernel_launch(void* const* d_in, const int* in_sizes, int n_in,
                              void* d_out, int out_size, void* d_ws, size_t ws_size,
                              hipStream_t stream)
{
    const float* feat_t   = (const float*)d_in[0];
    const float* feat_tm1 = (const float*)d_in[1];
    const float* agg_w    = (const float*)d_in[2];
    const float* agg_b    = (const float*)d_in[3];
    const float* wproj_w  = (const float*)d_in[4];
    const float* wproj_b  = (const float*)d_in[5];
    float* outp = (float*)d_out;
    (void)d_ws; (void)ws_size;

    agg_mono<<<512, 512, 0, stream>>>(feat_t, feat_tm1, agg_w, agg_b,
                                      wproj_w, wproj_b, outp);
}